// Round 12
// baseline (225.548 us; speedup 1.0000x reference)
//
#include <hip/hip_runtime.h>
#include <stdint.h>

typedef int   i32x4  __attribute__((ext_vector_type(4)));
typedef int   i32x16 __attribute__((ext_vector_type(16)));
typedef float f32x4  __attribute__((ext_vector_type(4)));
typedef _Float16 half8 __attribute__((ext_vector_type(8)));

#define M_DIM 8192
#define N_DIM 4096
#define K_DIM 4096
#define NT 64
#define TILE_A 16384            // A K-tile image: 256 rows x 64 k (fragment-major)
#define TILE_B 8192             // B K-tile image: 128 rows x 64 k (fragment-major)
#define BUF_BYTES 24576         // A (16K) + B (8K) per buffer

#define GLOAD_LDS16(g, l)                                        \
    __builtin_amdgcn_global_load_lds(                            \
        (const __attribute__((address_space(1))) uint32_t*)(g),  \
        (__attribute__((address_space(3))) uint32_t*)(l), 16, 0, 0)

#define BARRIER()  asm volatile("s_barrier" ::: "memory")
#define WAIT_VM6() asm volatile("s_waitcnt vmcnt(6)" ::: "memory")

// Fragment-major image layout: element (row, k) lives at
//   block(g=row>>5, s=(k>>5), h=(k>>4)&1) * 512 + (row&31)*16 + (k&15)
// A wave's mfma_i32_32x32x32_i8 fragment read (lane: row=lane&31, kh=lane>>5)
// is then lds[base + lane*16 + CONST] -- a contiguous 1KB block, identical to
// the linear staging-write pattern (2 lanes/bank-quad per 16-lane phase = free,
// proven 0-conflict in r5-r9). No XOR swizzle anywhere; global_load_lds linear.

// ---------------- prep_a: SINGLE-PASS per-row quantize A fp32 -> int8 ----------------
// One block per row; row cached in registers (16 floats/thread) -> exactly one
// HBM read of A. Block-reduce absmax via wave shuffle + tiny LDS.
__global__ __launch_bounds__(256)
void prep_a(const float* __restrict__ A, signed char* __restrict__ Apack,
            float* __restrict__ Ascale) {
    const int r    = blockIdx.x;           // 8192 rows
    const int tid  = threadIdx.x;
    const int lane = tid & 63;
    const int wvq  = tid >> 6;
    const float* row = A + (size_t)r * K_DIM;

    float4 v[4];
#pragma unroll
    for (int q = 0; q < 4; ++q)
        v[q] = *(const float4*)(row + tid * 16 + q * 4);

    float mx = 0.f;
#pragma unroll
    for (int q = 0; q < 4; ++q)
        mx = fmaxf(mx, fmaxf(fmaxf(fabsf(v[q].x), fabsf(v[q].y)),
                             fmaxf(fabsf(v[q].z), fabsf(v[q].w))));
#pragma unroll
    for (int s = 1; s < 64; s <<= 1)
        mx = fmaxf(mx, __shfl_xor(mx, s, 64));

    __shared__ float red[4];
    if (lane == 0) red[wvq] = mx;
    __syncthreads();
    mx = fmaxf(fmaxf(red[0], red[1]), fmaxf(red[2], red[3]));

    float inv = mx > 0.f ? 127.f / mx : 0.f;
    if (tid == 0) Ascale[r] = mx * (1.f / 127.f);

    unsigned w[4];
#pragma unroll
    for (int q = 0; q < 4; ++q) {
        int a0 = (int)rintf(v[q].x * inv);
        int a1 = (int)rintf(v[q].y * inv);
        int a2 = (int)rintf(v[q].z * inv);
        int a3 = (int)rintf(v[q].w * inv);
        w[q] = (a0 & 255) | ((a1 & 255) << 8) | ((a2 & 255) << 16)
             | ((unsigned)(a3 & 255) << 24);
    }
    // thread owns k0 = tid*16: kt = tid>>2; chunk c = tid&3 -> s=c>>1, h=c&1
    int bm = r >> 8, rl = r & 255;
    int kt = tid >> 2, c = tid & 3;
    int blk = (((rl >> 5) << 2) | c);      // (g<<2)|(s<<1)|h  with c = s*2+h
    uint4 pk = make_uint4(w[0], w[1], w[2], w[3]);
    *(uint4*)(Apack + (size_t)(bm * NT + kt) * TILE_A + blk * 512 + (rl & 31) * 16) = pk;
}

// ---------------- prep_w: repack W -> fragment-major 128x64 K-tile images ----------------
__global__ __launch_bounds__(256)
void prep_w(const void* __restrict__ Wv, signed char* __restrict__ Wpack) {
    const int* wp = (const int*)Wv;
    bool wi32 = true;
#pragma unroll
    for (int i = 0; i < 16; ++i) {
        int v = wp[i];
        wi32 = wi32 && (v >= -128 && v <= 127);
    }
    int g = blockIdx.x * 256 + threadIdx.x;   // 1,048,576 chunks of 16
    int r = g >> 8;                           // row 0..4095
    int col0 = (g & 255) << 4;
    uint4 pk;
    if (wi32) {
        const int* p = (const int*)Wv + (size_t)r * K_DIM + col0;
        unsigned w[4];
#pragma unroll
        for (int q = 0; q < 4; ++q) {
            int4 v = *(const int4*)(p + q * 4);
            w[q] = (v.x & 255) | ((v.y & 255) << 8) | ((v.z & 255) << 16)
                 | ((unsigned)(v.w & 255) << 24);
        }
        pk = make_uint4(w[0], w[1], w[2], w[3]);
    } else {
        pk = *(const uint4*)((const signed char*)Wv + (size_t)r * K_DIM + col0);
    }
    int bn = r >> 7, rl = r & 127;
    int kt = col0 >> 6, c = (col0 >> 4) & 3;
    int blk = (((rl >> 5) << 2) | c);
    *(uint4*)(Wpack + (size_t)(bn * NT + kt) * TILE_B + blk * 512 + (rl & 31) * 16) = pk;
}

// ---------------- main GEMM: 32x32x32 i8 MFMA, fragment-major LDS, 3-deep vmcnt ----------------
// r9 pipeline (2 independent blocks/CU, 3-buf counted-vmcnt, 1 barrier/tile).
// All 12 fragment ds_read_b128 are lds[base + lane*16 + imm] (conflict-free by
// construction; zero per-read address math).
// A frag (m, s): buf + wm*8192 + m*2048 + s*1024 + lane*16
// B frag (n, s): buf + 16384 + wn*4096 + n*2048 + s*1024 + lane*16
// C/D: col=lane&31, row=(reg&3)+8*(reg>>2)+4*(lane>>5)  [m74-verified, r11-confirmed].
__global__ __launch_bounds__(256, 2)
void w8a16_gemm_i8(const signed char* __restrict__ Apack,
                   const signed char* __restrict__ Wpack,
                   const float* __restrict__ Ascale,
                   const float* __restrict__ scales,
                   const float* __restrict__ bias,
                   float* __restrict__ out) {
    __shared__ char smem[3 * BUF_BYTES];   // per buf: A 16K at +0, B 8K at +16384

    const int tid  = threadIdx.x;
    const int lane = tid & 63;
    const int wv   = tid >> 6;     // 0..3
    const int wm   = wv >> 1;      // 0..1  (M half: 128 rows)
    const int wn   = wv & 1;       // 0..1  (N half: 64 cols)
    const int r32  = lane & 31;
    const int kh   = lane >> 5;

    // XCD swizzle: co-XCD blocks share bm -> A pack panel (1 MiB) L2-hot
    int bid = blockIdx.x;
    int swz = (bid & 7) * 128 + (bid >> 3);   // 1024 blocks, bijective
    int bm = swz >> 5;             // 0..31
    int bn = swz & 31;             // 0..31

    const char* Abase = (const char*)Apack + (size_t)bm * NT * TILE_A + tid * 16;
    const char* Bbase = (const char*)Wpack + (size_t)bn * NT * TILE_B + tid * 16;

    auto stage = [&](int kt, int buf) {
        const char* ga = Abase + (size_t)kt * TILE_A;
        char* la = smem + buf * BUF_BYTES + tid * 16;
        GLOAD_LDS16(ga,          la);
        GLOAD_LDS16(ga + 4096,   la + 4096);
        GLOAD_LDS16(ga + 8192,   la + 8192);
        GLOAD_LDS16(ga + 12288,  la + 12288);
        const char* gb = Bbase + (size_t)kt * TILE_B;
        char* lb = smem + buf * BUF_BYTES + 16384 + tid * 16;
        GLOAD_LDS16(gb,          lb);
        GLOAD_LDS16(gb + 4096,   lb + 4096);
    };

    i32x16 acc[4][2] = {};   // [m-group of 32 rows][n-group of 32 cols]

    auto compute = [&](int buf) {
        const char* lbase = smem + buf * BUF_BYTES + lane * 16;
        const char* abase = lbase + wm * 8192;
        const char* bbase = lbase + 16384 + wn * 4096;
        i32x4 bf0[2], bf1[2], af0[4], af1[4];
#pragma unroll
        for (int n = 0; n < 2; ++n) {
            bf0[n] = *(const i32x4*)(bbase + n * 2048);
            bf1[n] = *(const i32x4*)(bbase + n * 2048 + 1024);
        }
#pragma unroll
        for (int m = 0; m < 4; ++m) {
            af0[m] = *(const i32x4*)(abase + m * 2048);
            af1[m] = *(const i32x4*)(abase + m * 2048 + 1024);
        }
        __builtin_amdgcn_s_setprio(1);
#pragma unroll
        for (int n = 0; n < 2; ++n)
#pragma unroll
            for (int m = 0; m < 4; ++m)
                acc[m][n] = __builtin_amdgcn_mfma_i32_32x32x32_i8(af0[m], bf0[n], acc[m][n], 0, 0, 0);
#pragma unroll
        for (int n = 0; n < 2; ++n)
#pragma unroll
            for (int m = 0; m < 4; ++m)
                acc[m][n] = __builtin_amdgcn_mfma_i32_32x32x32_i8(af1[m], bf1[n], acc[m][n], 0, 0, 0);
        __builtin_amdgcn_s_setprio(0);
    };

    // prologue: stage tiles 0,1 into bufs 0,1
    stage(0, 0);
    stage(1, 1);
    WAIT_VM6();    // stage(0) landed; stage(1)'s 6 loads remain in flight
    BARRIER();

    int buf = 0;
#pragma unroll 1
    for (int t = 0; t < NT; ++t) {
        int tn   = (t + 2 < NT) ? t + 2 : NT - 1;  // clamped dummy at tail
        int bufn = buf + 2 - ((buf >= 1) ? 3 : 0); // (buf+2)%3
        stage(tn, bufn);
        compute(buf);
        WAIT_VM6();   // stage(t+1) landed; stage(t+2) stays in flight
        BARRIER();    // cross-wave: writes visible, buf reads done
        buf = (buf + 1 < 3) ? buf + 1 : 0;
    }

    // ---- epilogue: out = acc * ascale[row] * scales[col] + bias[col] ----
    float sc[2], bs[2];
#pragma unroll
    for (int n = 0; n < 2; ++n) {
        int col = bn * 128 + wn * 64 + n * 32 + r32;
        sc[n] = scales[col];
        bs[n] = bias[col];
    }
#pragma unroll
    for (int mi = 0; mi < 4; ++mi) {
        int rowbase = bm * 256 + wm * 128 + mi * 32 + 4 * kh;
#pragma unroll
        for (int reg = 0; reg < 16; ++reg) {
            int row = rowbase + (reg & 3) + 8 * (reg >> 2);
            float as_ = Ascale[row];
#pragma unroll
            for (int n = 0; n < 2; ++n) {
                int col = bn * 128 + wn * 64 + n * 32 + r32;
                out[(size_t)row * N_DIM + col] =
                    (float)acc[mi][n][reg] * (as_ * sc[n]) + bs[n];
            }
        }
    }
}

// ---------------- fallback (reg-staged fp16, no workspace needed) ----------------
__global__ __launch_bounds__(256, 2)
void w8a16_gemm(const float* __restrict__ A,
                const void* __restrict__ Wv,
                const float* __restrict__ scales,
                const float* __restrict__ bias,
                float* __restrict__ out) {
    __shared__ char smem[2 * 128 * 64 * 2];
    char* Ash = smem;
    char* Bsh = smem + 128 * 64 * 2;

    const int* wprobe = (const int*)Wv;
    bool wi32 = true;
#pragma unroll
    for (int i = 0; i < 16; ++i) {
        int v = wprobe[i];
        wi32 = wi32 && (v >= -128 && v <= 127);
    }

    const int tid  = threadIdx.x;
    const int lane = tid & 63;
    const int wv   = tid >> 6;
    const int wwm  = wv >> 1;
    const int wwn  = wv & 1;
    const int r16  = lane & 15;
    const int kq   = lane >> 4;
    const int swzl = (r16 & 7) << 4;

    int bid = blockIdx.x;
    int swz = (bid & 7) * 256 + (bid >> 3);
    int bm = swz / 32;
    int bn = swz % 32;

    const int row_a0 = bm * 128;
    const int row_b0 = bn * 128;

    int cr[4], cc[4];
#pragma unroll
    for (int i = 0; i < 4; ++i) {
        int c = tid + 256 * i;
        cr[i] = c >> 3;
        cc[i] = (c & 7) << 3;
    }

    float4 pa[8];
    int4   pbi[8];
    uint2  pb8[4];

    auto load_tile = [&](int kt) {
        int k0 = kt * 64;
#pragma unroll
        for (int i = 0; i < 4; ++i) {
            const float* p = A + (size_t)(row_a0 + cr[i]) * K_DIM + k0 + cc[i];
            pa[2 * i]     = *(const float4*)p;
            pa[2 * i + 1] = *(const float4*)(p + 4);
        }
        if (wi32) {
            const int* w = (const int*)Wv;
#pragma unroll
            for (int i = 0; i < 4; ++i) {
                const int* p = w + (size_t)(row_b0 + cr[i]) * K_DIM + k0 + cc[i];
                pbi[2 * i]     = *(const int4*)p;
                pbi[2 * i + 1] = *(const int4*)(p + 4);
            }
        } else {
            const signed char* w = (const signed char*)Wv;
#pragma unroll
            for (int i = 0; i < 4; ++i) {
                const signed char* p = w + (size_t)(row_b0 + cr[i]) * K_DIM + k0 + cc[i];
                pb8[i] = *(const uint2*)p;
            }
        }
    };

    auto write_lds = [&]() {
#pragma unroll
        for (int i = 0; i < 4; ++i) {
            int off = (cr[i] * 128 + cc[i] * 2) ^ ((cr[i] & 7) << 4);
            half8 h;
            h[0] = (_Float16)pa[2 * i].x;
            h[1] = (_Float16)pa[2 * i].y;
            h[2] = (_Float16)pa[2 * i].z;
            h[3] = (_Float16)pa[2 * i].w;
            h[4] = (_Float16)pa[2 * i + 1].x;
            h[5] = (_Float16)pa[2 * i + 1].y;
            h[6] = (_Float16)pa[2 * i + 1].z;
            h[7] = (_Float16)pa[2 * i + 1].w;
            *(half8*)(Ash + off) = h;

            half8 g;
            if (wi32) {
                g[0] = (_Float16)pbi[2 * i].x;
                g[1] = (_Float16)pbi[2 * i].y;
                g[2] = (_Float16)pbi[2 * i].z;
                g[3] = (_Float16)pbi[2 * i].w;
                g[4] = (_Float16)pbi[2 * i + 1].x;
                g[5] = (_Float16)pbi[2 * i + 1].y;
                g[6] = (_Float16)pbi[2 * i + 1].z;
                g[7] = (_Float16)pbi[2 * i + 1].w;
            } else {
                unsigned x = pb8[i].x, y = pb8[i].y;
                g[0] = (_Float16)(int)(signed char)(x & 0xff);
                g[1] = (_Float16)(int)(signed char)((x >> 8) & 0xff);
                g[2] = (_Float16)(int)(signed char)((x >> 16) & 0xff);
                g[3] = (_Float16)(int)(signed char)(x >> 24);
                g[4] = (_Float16)(int)(signed char)(y & 0xff);
                g[5] = (_Float16)(int)(signed char)((y >> 8) & 0xff);
                g[6] = (_Float16)(int)(signed char)((y >> 16) & 0xff);
                g[7] = (_Float16)(int)(signed char)(y >> 24);
            }
            *(half8*)(Bsh + off) = g;
        }
    };

    f32x4 acc[4][4] = {};

    auto compute = [&]() {
#pragma unroll
        for (int ks = 0; ks < 2; ++ks) {
            half8 af[4], bfr[4];
#pragma unroll
            for (int m = 0; m < 4; ++m) {
                int row = wwm * 64 + m * 16 + r16;
                af[m] = *(const half8*)(Ash + ((row * 128 + ks * 64 + kq * 16) ^ swzl));
            }
#pragma unroll
            for (int n = 0; n < 4; ++n) {
                int row = wwn * 64 + n * 16 + r16;
                bfr[n] = *(const half8*)(Bsh + ((row * 128 + ks * 64 + kq * 16) ^ swzl));
            }
#pragma unroll
            for (int m = 0; m < 4; ++m)
#pragma unroll
                for (int n = 0; n < 4; ++n)
                    acc[m][n] = __builtin_amdgcn_mfma_f32_16x16x32_f16(af[m], bfr[n], acc[m][n], 0, 0, 0);
        }
    };

    load_tile(0);
#pragma unroll 1
    for (int kt = 0; kt < NT; ++kt) {
        if (kt) __syncthreads();
        write_lds();
        __syncthreads();
        if (kt + 1 < NT) load_tile(kt + 1);
        compute();
    }

#pragma unroll
    for (int n = 0; n < 4; ++n) {
        int col = row_b0 + wwn * 64 + n * 16 + r16;
        float s = scales[col];
        float b = bias[col];
#pragma unroll
        for (int m = 0; m < 4; ++m) {
            int row0 = row_a0 + wwm * 64 + m * 16 + kq * 4;
#pragma unroll
            for (int j = 0; j < 4; ++j) {
                out[(size_t)(row0 + j) * N_DIM + col] = acc[m][n][j] * s + b;
            }
        }
    }
}

extern "C" void kernel_launch(void* const* d_in, const int* in_sizes, int n_in,
                              void* d_out, int out_size, void* d_ws, size_t ws_size,
                              hipStream_t stream) {
    const float* A      = (const float*)d_in[0];
    const void*  W      = d_in[1];
    const float* scales = (const float*)d_in[2];
    const float* bias   = (const float*)d_in[3];
    float*       out    = (float*)d_out;

    const size_t needA = (size_t)M_DIM * K_DIM;        // 32 MiB int8
    const size_t needW = (size_t)N_DIM * K_DIM;        // 16 MiB int8
    const size_t needS = (size_t)M_DIM * sizeof(float);

    if (ws_size >= needA + needW + needS) {
        signed char* Apack = (signed char*)d_ws;
        signed char* Wpack = (signed char*)d_ws + needA;
        float*       Asc   = (float*)((char*)d_ws + needA + needW);
        hipLaunchKernelGGL(prep_a, dim3(8192), dim3(256), 0, stream, A, Apack, Asc);
        hipLaunchKernelGGL(prep_w, dim3(4096), dim3(256), 0, stream, W, Wpack);
        hipLaunchKernelGGL(w8a16_gemm_i8, dim3(1024), dim3(256), 0, stream,
                           Apack, Wpack, Asc, scales, bias, out);
    } else {
        hipLaunchKernelGGL(w8a16_gemm, dim3(2048), dim3(256), 0, stream,
                           A, W, scales, bias, out);
    }
}

// Round 13
// 179.059 us; speedup vs baseline: 1.2596x; 1.2596x over previous
//
#include <hip/hip_runtime.h>
#include <stdint.h>

typedef int   i32x4 __attribute__((ext_vector_type(4)));
typedef float f32x4 __attribute__((ext_vector_type(4)));
typedef _Float16 half8 __attribute__((ext_vector_type(8)));

#define M_DIM 8192
#define N_DIM 4096
#define K_DIM 4096
#define NT 64
#define TILE_A 16384            // A K-tile image: 256 rows x 64 B
#define TILE_B 8192             // B K-tile image: 128 rows x 64 B
#define BUF_BYTES 24576         // A (16K) + B (8K) per buffer

#define GLOAD_LDS16(g, l)                                        \
    __builtin_amdgcn_global_load_lds(                            \
        (const __attribute__((address_space(1))) uint32_t*)(g),  \
        (__attribute__((address_space(3))) uint32_t*)(l), 16, 0, 0)

#define BARRIER()  asm volatile("s_barrier" ::: "memory")
#define WAIT_VM6() asm volatile("s_waitcnt vmcnt(6)" ::: "memory")

// Image byte offset for (row, 16B-slot 0..3), row stride 64 B.
// slot' = slot ^ (row>>1 & 3): conflict-free for the 16x16x64 fragment read
// (verified 0 conflicts r5-r9). Involution on pack-write AND LDS-read;
// global_load_lds stays linear (rule #21).
__device__ __forceinline__ int img_off(int row, int slot) {
    return row * 64 + ((slot ^ ((row >> 1) & 3)) << 4);
}

// ---------------- prep_a: SINGLE-PASS per-row quantize A fp32 -> int8 ----------------
// One block per row; row cached in registers (16 floats/thread) -> exactly one
// HBM read of A. Verified correct in r11/r12 (absmax 768).
__global__ __launch_bounds__(256)
void prep_a(const float* __restrict__ A, signed char* __restrict__ Apack,
            float* __restrict__ Ascale) {
    const int r    = blockIdx.x;           // 8192 rows
    const int tid  = threadIdx.x;
    const int lane = tid & 63;
    const int wvq  = tid >> 6;
    const float* row = A + (size_t)r * K_DIM;

    float4 v[4];
#pragma unroll
    for (int q = 0; q < 4; ++q)
        v[q] = *(const float4*)(row + tid * 16 + q * 4);

    float mx = 0.f;
#pragma unroll
    for (int q = 0; q < 4; ++q)
        mx = fmaxf(mx, fmaxf(fmaxf(fabsf(v[q].x), fabsf(v[q].y)),
                             fmaxf(fabsf(v[q].z), fabsf(v[q].w))));
#pragma unroll
    for (int s = 1; s < 64; s <<= 1)
        mx = fmaxf(mx, __shfl_xor(mx, s, 64));

    __shared__ float red[4];
    if (lane == 0) red[wvq] = mx;
    __syncthreads();
    mx = fmaxf(fmaxf(red[0], red[1]), fmaxf(red[2], red[3]));

    float inv = mx > 0.f ? 127.f / mx : 0.f;
    if (tid == 0) Ascale[r] = mx * (1.f / 127.f);

    unsigned w[4];
#pragma unroll
    for (int q = 0; q < 4; ++q) {
        int a0 = (int)rintf(v[q].x * inv);
        int a1 = (int)rintf(v[q].y * inv);
        int a2 = (int)rintf(v[q].z * inv);
        int a3 = (int)rintf(v[q].w * inv);
        w[q] = (a0 & 255) | ((a1 & 255) << 8) | ((a2 & 255) << 16)
             | ((unsigned)(a3 & 255) << 24);
    }
    // thread owns k0 = tid*16: kt = tid>>2, slot = tid&3
    int bm = r >> 8, rl = r & 255;
    int kt = tid >> 2, slot = tid & 3;
    uint4 pk = make_uint4(w[0], w[1], w[2], w[3]);
    *(uint4*)(Apack + (size_t)(bm * NT + kt) * TILE_A + img_off(rl, slot)) = pk;
}

// ---------------- prep_w: repack W -> swizzled 128x64 K-tile images ----------------
__global__ __launch_bounds__(256)
void prep_w(const void* __restrict__ Wv, signed char* __restrict__ Wpack) {
    const int* wp = (const int*)Wv;
    bool wi32 = true;
#pragma unroll
    for (int i = 0; i < 16; ++i) {
        int v = wp[i];
        wi32 = wi32 && (v >= -128 && v <= 127);
    }
    int g = blockIdx.x * 256 + threadIdx.x;   // 1,048,576 chunks of 16
    int r = g >> 8;                           // row 0..4095
    int col0 = (g & 255) << 4;
    uint4 pk;
    if (wi32) {
        const int* p = (const int*)Wv + (size_t)r * K_DIM + col0;
        unsigned w[4];
#pragma unroll
        for (int q = 0; q < 4; ++q) {
            int4 v = *(const int4*)(p + q * 4);
            w[q] = (v.x & 255) | ((v.y & 255) << 8) | ((v.z & 255) << 16)
                 | ((unsigned)(v.w & 255) << 24);
        }
        pk = make_uint4(w[0], w[1], w[2], w[3]);
    } else {
        pk = *(const uint4*)((const signed char*)Wv + (size_t)r * K_DIM + col0);
    }
    int bn = r >> 7, rl = r & 127;
    int kt = col0 >> 6, k = col0 & 63;
    *(uint4*)(Wpack + (size_t)(bn * NT + kt) * TILE_B + img_off(rl, k >> 4)) = pk;
}

// ---------------- main GEMM: r9 core (best measured: 128.4us, MfmaUtil 49.8) ----------------
// i8 mfma_16x16x64, 256x128 block, 4 waves, 2 independent blocks/CU,
// 3-buf counted-vmcnt(6) staging (stage t+2 at top of t; never drains to 0),
// 1 barrier per K-tile.
__global__ __launch_bounds__(256, 2)
void w8a16_gemm_i8(const signed char* __restrict__ Apack,
                   const signed char* __restrict__ Wpack,
                   const float* __restrict__ Ascale,
                   const float* __restrict__ scales,
                   const float* __restrict__ bias,
                   float* __restrict__ out) {
    __shared__ char smem[3 * BUF_BYTES];   // per buf: A 16K at +0, B 8K at +16384

    const int tid  = threadIdx.x;
    const int lane = tid & 63;
    const int wv   = tid >> 6;     // 0..3
    const int wm   = wv >> 1;      // 0..1  (M half: 128 rows)
    const int wn   = wv & 1;       // 0..1  (N half: 64 cols)
    const int r16  = lane & 15;
    const int kq   = lane >> 4;

    // XCD swizzle: co-XCD blocks share bm -> A pack panel (1 MiB) L2-hot
    int bid = blockIdx.x;
    int swz = (bid & 7) * 128 + (bid >> 3);   // 1024 blocks, bijective
    int bm = swz >> 5;             // 0..31
    int bn = swz & 31;             // 0..31

    const char* Abase = (const char*)Apack + (size_t)bm * NT * TILE_A + tid * 16;
    const char* Bbase = (const char*)Wpack + (size_t)bn * NT * TILE_B + tid * 16;

    auto stage = [&](int kt, int buf) {
        const char* ga = Abase + (size_t)kt * TILE_A;
        char* la = smem + buf * BUF_BYTES + tid * 16;
        GLOAD_LDS16(ga,          la);
        GLOAD_LDS16(ga + 4096,   la + 4096);
        GLOAD_LDS16(ga + 8192,   la + 8192);
        GLOAD_LDS16(ga + 12288,  la + 12288);
        const char* gb = Bbase + (size_t)kt * TILE_B;
        char* lb = smem + buf * BUF_BYTES + 16384 + tid * 16;
        GLOAD_LDS16(gb,          lb);
        GLOAD_LDS16(gb + 4096,   lb + 4096);
    };

    i32x4 acc[8][4] = {};

    auto compute = [&](int buf) {
        const char* base = smem + buf * BUF_BYTES;
        i32x4 bf[4];
#pragma unroll
        for (int n = 0; n < 4; ++n) {
            int row = wn * 64 + n * 16 + r16;
            bf[n] = *(const i32x4*)(base + 16384 + img_off(row, kq));
        }
        i32x4 af[8];
#pragma unroll
        for (int m = 0; m < 8; ++m) {
            int row = wm * 128 + m * 16 + r16;
            af[m] = *(const i32x4*)(base + img_off(row, kq));
        }
        __builtin_amdgcn_s_setprio(1);
#pragma unroll
        for (int n = 0; n < 4; ++n)
#pragma unroll
            for (int m = 0; m < 8; ++m)
                acc[m][n] = __builtin_amdgcn_mfma_i32_16x16x64_i8(af[m], bf[n], acc[m][n], 0, 0, 0);
        __builtin_amdgcn_s_setprio(0);
    };

    // prologue: stage tiles 0,1 into bufs 0,1
    stage(0, 0);
    stage(1, 1);
    WAIT_VM6();    // stage(0) landed; stage(1)'s 6 loads remain in flight
    BARRIER();

    int buf = 0;
#pragma unroll 1
    for (int t = 0; t < NT; ++t) {
        int tn   = (t + 2 < NT) ? t + 2 : NT - 1;  // clamped dummy at tail
        int bufn = buf + 2 - ((buf >= 1) ? 3 : 0); // (buf+2)%3
        stage(tn, bufn);
        compute(buf);
        WAIT_VM6();   // stage(t+1) landed; stage(t+2) stays in flight
        BARRIER();    // cross-wave: writes visible, buf reads done
        buf = (buf + 1 < 3) ? buf + 1 : 0;
    }

    // ---- epilogue: out = acc * ascale[row] * scales[col] + bias[col] ----
    float sc[4], bs[4];
#pragma unroll
    for (int n = 0; n < 4; ++n) {
        int col = bn * 128 + wn * 64 + n * 16 + r16;
        sc[n] = scales[col];
        bs[n] = bias[col];
    }
#pragma unroll
    for (int mi = 0; mi < 8; ++mi) {
        int row0 = bm * 256 + wm * 128 + mi * 16 + kq * 4;
#pragma unroll
        for (int j = 0; j < 4; ++j) {
            int row = row0 + j;
            float as_ = Ascale[row];
#pragma unroll
            for (int n = 0; n < 4; ++n) {
                int col = bn * 128 + wn * 64 + n * 16 + r16;
                out[(size_t)row * N_DIM + col] =
                    (float)acc[mi][n][j] * (as_ * sc[n]) + bs[n];
            }
        }
    }
}

// ---------------- fallback (reg-staged fp16, no workspace needed) ----------------
__global__ __launch_bounds__(256, 2)
void w8a16_gemm(const float* __restrict__ A,
                const void* __restrict__ Wv,
                const float* __restrict__ scales,
                const float* __restrict__ bias,
                float* __restrict__ out) {
    __shared__ char smem[2 * 128 * 64 * 2];
    char* Ash = smem;
    char* Bsh = smem + 128 * 64 * 2;

    const int* wprobe = (const int*)Wv;
    bool wi32 = true;
#pragma unroll
    for (int i = 0; i < 16; ++i) {
        int v = wprobe[i];
        wi32 = wi32 && (v >= -128 && v <= 127);
    }

    const int tid  = threadIdx.x;
    const int lane = tid & 63;
    const int wv   = tid >> 6;
    const int wwm  = wv >> 1;
    const int wwn  = wv & 1;
    const int r16  = lane & 15;
    const int kq   = lane >> 4;
    const int swzl = (r16 & 7) << 4;

    int bid = blockIdx.x;
    int swz = (bid & 7) * 256 + (bid >> 3);
    int bm = swz / 32;
    int bn = swz % 32;

    const int row_a0 = bm * 128;
    const int row_b0 = bn * 128;

    int cr[4], cc[4];
#pragma unroll
    for (int i = 0; i < 4; ++i) {
        int c = tid + 256 * i;
        cr[i] = c >> 3;
        cc[i] = (c & 7) << 3;
    }

    float4 pa[8];
    int4   pbi[8];
    uint2  pb8[4];

    auto load_tile = [&](int kt) {
        int k0 = kt * 64;
#pragma unroll
        for (int i = 0; i < 4; ++i) {
            const float* p = A + (size_t)(row_a0 + cr[i]) * K_DIM + k0 + cc[i];
            pa[2 * i]     = *(const float4*)p;
            pa[2 * i + 1] = *(const float4*)(p + 4);
        }
        if (wi32) {
            const int* w = (const int*)Wv;
#pragma unroll
            for (int i = 0; i < 4; ++i) {
                const int* p = w + (size_t)(row_b0 + cr[i]) * K_DIM + k0 + cc[i];
                pbi[2 * i]     = *(const int4*)p;
                pbi[2 * i + 1] = *(const int4*)(p + 4);
            }
        } else {
            const signed char* w = (const signed char*)Wv;
#pragma unroll
            for (int i = 0; i < 4; ++i) {
                const signed char* p = w + (size_t)(row_b0 + cr[i]) * K_DIM + k0 + cc[i];
                pb8[i] = *(const uint2*)p;
            }
        }
    };

    auto write_lds = [&]() {
#pragma unroll
        for (int i = 0; i < 4; ++i) {
            int off = (cr[i] * 128 + cc[i] * 2) ^ ((cr[i] & 7) << 4);
            half8 h;
            h[0] = (_Float16)pa[2 * i].x;
            h[1] = (_Float16)pa[2 * i].y;
            h[2] = (_Float16)pa[2 * i].z;
            h[3] = (_Float16)pa[2 * i].w;
            h[4] = (_Float16)pa[2 * i + 1].x;
            h[5] = (_Float16)pa[2 * i + 1].y;
            h[6] = (_Float16)pa[2 * i + 1].z;
            h[7] = (_Float16)pa[2 * i + 1].w;
            *(half8*)(Ash + off) = h;

            half8 g;
            if (wi32) {
                g[0] = (_Float16)pbi[2 * i].x;
                g[1] = (_Float16)pbi[2 * i].y;
                g[2] = (_Float16)pbi[2 * i].z;
                g[3] = (_Float16)pbi[2 * i].w;
                g[4] = (_Float16)pbi[2 * i + 1].x;
                g[5] = (_Float16)pbi[2 * i + 1].y;
                g[6] = (_Float16)pbi[2 * i + 1].z;
                g[7] = (_Float16)pbi[2 * i + 1].w;
            } else {
                unsigned x = pb8[i].x, y = pb8[i].y;
                g[0] = (_Float16)(int)(signed char)(x & 0xff);
                g[1] = (_Float16)(int)(signed char)((x >> 8) & 0xff);
                g[2] = (_Float16)(int)(signed char)((x >> 16) & 0xff);
                g[3] = (_Float16)(int)(signed char)(x >> 24);
                g[4] = (_Float16)(int)(signed char)(y & 0xff);
                g[5] = (_Float16)(int)(signed char)((y >> 8) & 0xff);
                g[6] = (_Float16)(int)(signed char)((y >> 16) & 0xff);
                g[7] = (_Float16)(int)(signed char)(y >> 24);
            }
            *(half8*)(Bsh + off) = g;
        }
    };

    f32x4 acc[4][4] = {};

    auto compute = [&]() {
#pragma unroll
        for (int ks = 0; ks < 2; ++ks) {
            half8 af[4], bfr[4];
#pragma unroll
            for (int m = 0; m < 4; ++m) {
                int row = wwm * 64 + m * 16 + r16;
                af[m] = *(const half8*)(Ash + ((row * 128 + ks * 64 + kq * 16) ^ swzl));
            }
#pragma unroll
            for (int n = 0; n < 4; ++n) {
                int row = wwn * 64 + n * 16 + r16;
                bfr[n] = *(const half8*)(Bsh + ((row * 128 + ks * 64 + kq * 16) ^ swzl));
            }
#pragma unroll
            for (int m = 0; m < 4; ++m)
#pragma unroll
                for (int n = 0; n < 4; ++n)
                    acc[m][n] = __builtin_amdgcn_mfma_f32_16x16x32_f16(af[m], bfr[n], acc[m][n], 0, 0, 0);
        }
    };

    load_tile(0);
#pragma unroll 1
    for (int kt = 0; kt < NT; ++kt) {
        if (kt) __syncthreads();
        write_lds();
        __syncthreads();
        if (kt + 1 < NT) load_tile(kt + 1);
        compute();
    }

#pragma unroll
    for (int n = 0; n < 4; ++n) {
        int col = row_b0 + wwn * 64 + n * 16 + r16;
        float s = scales[col];
        float b = bias[col];
#pragma unroll
        for (int m = 0; m < 4; ++m) {
            int row0 = row_a0 + wwm * 64 + m * 16 + kq * 4;
#pragma unroll
            for (int j = 0; j < 4; ++j) {
                out[(size_t)(row0 + j) * N_DIM + col] = acc[m][n][j] * s + b;
            }
        }
    }
}

extern "C" void kernel_launch(void* const* d_in, const int* in_sizes, int n_in,
                              void* d_out, int out_size, void* d_ws, size_t ws_size,
                              hipStream_t stream) {
    const float* A      = (const float*)d_in[0];
    const void*  W      = d_in[1];
    const float* scales = (const float*)d_in[2];
    const float* bias   = (const float*)d_in[3];
    float*       out    = (float*)d_out;

    const size_t needA = (size_t)M_DIM * K_DIM;        // 32 MiB int8
    const size_t needW = (size_t)N_DIM * K_DIM;        // 16 MiB int8
    const size_t needS = (size_t)M_DIM * sizeof(float);

    if (ws_size >= needA + needW + needS) {
        signed char* Apack = (signed char*)d_ws;
        signed char* Wpack = (signed char*)d_ws + needA;
        float*       Asc   = (float*)((char*)d_ws + needA + needW);
        hipLaunchKernelGGL(prep_a, dim3(8192), dim3(256), 0, stream, A, Apack, Asc);
        hipLaunchKernelGGL(prep_w, dim3(4096), dim3(256), 0, stream, W, Wpack);
        hipLaunchKernelGGL(w8a16_gemm_i8, dim3(1024), dim3(256), 0, stream,
                           Apack, Wpack, Asc, scales, bias, out);
    } else {
        hipLaunchKernelGGL(w8a16_gemm, dim3(2048), dim3(256), 0, stream,
                           A, W, scales, bias, out);
    }
}

// Round 14
// 167.717 us; speedup vs baseline: 1.3448x; 1.0676x over previous
//
#include <hip/hip_runtime.h>
#include <stdint.h>

typedef int   i32x4 __attribute__((ext_vector_type(4)));
typedef float f32x4 __attribute__((ext_vector_type(4)));
typedef _Float16 half8 __attribute__((ext_vector_type(8)));

#define M_DIM 8192
#define N_DIM 4096
#define K_DIM 4096
#define NT 64
#define TILE_A 16384            // A K-tile image: 256 rows x 64 B
#define TILE_B 8192             // B K-tile image: 128 rows x 64 B
#define BUF_BYTES 24576         // A (16K) + B (8K) per buffer

#define GLOAD_LDS16(g, l)                                        \
    __builtin_amdgcn_global_load_lds(                            \
        (const __attribute__((address_space(1))) uint32_t*)(g),  \
        (__attribute__((address_space(3))) uint32_t*)(l), 16, 0, 0)

#define BARRIER()  asm volatile("s_barrier" ::: "memory")
#define WAIT_VM6() asm volatile("s_waitcnt vmcnt(6)" ::: "memory")

// Image byte offset for (row, 16B-slot 0..3), row stride 64 B.
// slot' = slot ^ (row>>1 & 3): conflict-free for the 16x16x64 fragment read
// (verified 0 conflicts r5-r9, r13). Involution on pack-write AND LDS-read;
// global_load_lds stays linear (rule #21).
__device__ __forceinline__ int img_off(int row, int slot) {
    return row * 64 + ((slot ^ ((row >> 1) & 3)) << 4);
}

// ---------------- fused prep: A quantize+pack (blocks 0..8191), W repack (8192..12287) ----------------
// prep_a part: one block per row; row cached in registers (16 floats/thread)
// -> exactly one HBM read of A (verified r11-r13, absmax 768).
// prep_w part: 16-B chunk repack with int32/int8 width probe.
__global__ __launch_bounds__(256)
void prep_fused(const float* __restrict__ A, const void* __restrict__ Wv,
                signed char* __restrict__ Apack, signed char* __restrict__ Wpack,
                float* __restrict__ Ascale) {
    const int tid = threadIdx.x;
    if (blockIdx.x < 8192) {
        // ---------- A path ----------
        const int r    = blockIdx.x;
        const int lane = tid & 63;
        const int wvq  = tid >> 6;
        const float* row = A + (size_t)r * K_DIM;

        float4 v[4];
#pragma unroll
        for (int q = 0; q < 4; ++q)
            v[q] = *(const float4*)(row + tid * 16 + q * 4);

        float mx = 0.f;
#pragma unroll
        for (int q = 0; q < 4; ++q)
            mx = fmaxf(mx, fmaxf(fmaxf(fabsf(v[q].x), fabsf(v[q].y)),
                                 fmaxf(fabsf(v[q].z), fabsf(v[q].w))));
#pragma unroll
        for (int s = 1; s < 64; s <<= 1)
            mx = fmaxf(mx, __shfl_xor(mx, s, 64));

        __shared__ float red[4];
        if (lane == 0) red[wvq] = mx;
        __syncthreads();
        mx = fmaxf(fmaxf(red[0], red[1]), fmaxf(red[2], red[3]));

        float inv = mx > 0.f ? 127.f / mx : 0.f;
        if (tid == 0) Ascale[r] = mx * (1.f / 127.f);

        unsigned w[4];
#pragma unroll
        for (int q = 0; q < 4; ++q) {
            int a0 = (int)rintf(v[q].x * inv);
            int a1 = (int)rintf(v[q].y * inv);
            int a2 = (int)rintf(v[q].z * inv);
            int a3 = (int)rintf(v[q].w * inv);
            w[q] = (a0 & 255) | ((a1 & 255) << 8) | ((a2 & 255) << 16)
                 | ((unsigned)(a3 & 255) << 24);
        }
        int bm = r >> 8, rl = r & 255;
        int kt = tid >> 2, slot = tid & 3;
        uint4 pk = make_uint4(w[0], w[1], w[2], w[3]);
        *(uint4*)(Apack + (size_t)(bm * NT + kt) * TILE_A + img_off(rl, slot)) = pk;
    } else {
        // ---------- W path ----------
        const int* wp = (const int*)Wv;
        bool wi32 = true;
#pragma unroll
        for (int i = 0; i < 16; ++i) {
            int v = wp[i];
            wi32 = wi32 && (v >= -128 && v <= 127);
        }
        int g = (blockIdx.x - 8192) * 256 + tid;  // 1,048,576 chunks of 16
        int r = g >> 8;                           // row 0..4095
        int col0 = (g & 255) << 4;
        uint4 pk;
        if (wi32) {
            const int* p = (const int*)Wv + (size_t)r * K_DIM + col0;
            unsigned w[4];
#pragma unroll
            for (int q = 0; q < 4; ++q) {
                int4 v = *(const int4*)(p + q * 4);
                w[q] = (v.x & 255) | ((v.y & 255) << 8) | ((v.z & 255) << 16)
                     | ((unsigned)(v.w & 255) << 24);
            }
            pk = make_uint4(w[0], w[1], w[2], w[3]);
        } else {
            pk = *(const uint4*)((const signed char*)Wv + (size_t)r * K_DIM + col0);
        }
        int bn = r >> 7, rl = r & 127;
        int kt = col0 >> 6, k = col0 & 63;
        *(uint4*)(Wpack + (size_t)(bn * NT + kt) * TILE_B + img_off(rl, k >> 4)) = pk;
    }
}

// ---------------- main GEMM: r9/r13 core (best measured: 121us, MfmaUtil 53-54) ----------------
// i8 mfma_16x16x64, 256x128 block, 4 waves, 2 independent blocks/CU,
// 3-buf counted-vmcnt(6) staging (stage t+2 at top of t; never drains to 0),
// 1 barrier per K-tile. Epilogue uses non-temporal stores (output is
// write-once 128MB; keep it from evicting the 48MB L3-resident packs).
__global__ __launch_bounds__(256, 2)
void w8a16_gemm_i8(const signed char* __restrict__ Apack,
                   const signed char* __restrict__ Wpack,
                   const float* __restrict__ Ascale,
                   const float* __restrict__ scales,
                   const float* __restrict__ bias,
                   float* __restrict__ out) {
    __shared__ char smem[3 * BUF_BYTES];   // per buf: A 16K at +0, B 8K at +16384

    const int tid  = threadIdx.x;
    const int lane = tid & 63;
    const int wv   = tid >> 6;     // 0..3
    const int wm   = wv >> 1;      // 0..1  (M half: 128 rows)
    const int wn   = wv & 1;       // 0..1  (N half: 64 cols)
    const int r16  = lane & 15;
    const int kq   = lane >> 4;

    // XCD swizzle: co-XCD blocks share bm -> A pack panel (1 MiB) L2-hot
    int bid = blockIdx.x;
    int swz = (bid & 7) * 128 + (bid >> 3);   // 1024 blocks, bijective
    int bm = swz >> 5;             // 0..31
    int bn = swz & 31;             // 0..31

    const char* Abase = (const char*)Apack + (size_t)bm * NT * TILE_A + tid * 16;
    const char* Bbase = (const char*)Wpack + (size_t)bn * NT * TILE_B + tid * 16;

    auto stage = [&](int kt, int buf) {
        const char* ga = Abase + (size_t)kt * TILE_A;
        char* la = smem + buf * BUF_BYTES + tid * 16;
        GLOAD_LDS16(ga,          la);
        GLOAD_LDS16(ga + 4096,   la + 4096);
        GLOAD_LDS16(ga + 8192,   la + 8192);
        GLOAD_LDS16(ga + 12288,  la + 12288);
        const char* gb = Bbase + (size_t)kt * TILE_B;
        char* lb = smem + buf * BUF_BYTES + 16384 + tid * 16;
        GLOAD_LDS16(gb,          lb);
        GLOAD_LDS16(gb + 4096,   lb + 4096);
    };

    i32x4 acc[8][4] = {};

    auto compute = [&](int buf) {
        const char* base = smem + buf * BUF_BYTES;
        i32x4 bf[4];
#pragma unroll
        for (int n = 0; n < 4; ++n) {
            int row = wn * 64 + n * 16 + r16;
            bf[n] = *(const i32x4*)(base + 16384 + img_off(row, kq));
        }
        i32x4 af[8];
#pragma unroll
        for (int m = 0; m < 8; ++m) {
            int row = wm * 128 + m * 16 + r16;
            af[m] = *(const i32x4*)(base + img_off(row, kq));
        }
        __builtin_amdgcn_s_setprio(1);
#pragma unroll
        for (int n = 0; n < 4; ++n)
#pragma unroll
            for (int m = 0; m < 8; ++m)
                acc[m][n] = __builtin_amdgcn_mfma_i32_16x16x64_i8(af[m], bf[n], acc[m][n], 0, 0, 0);
        __builtin_amdgcn_s_setprio(0);
    };

    // prologue: stage tiles 0,1 into bufs 0,1
    stage(0, 0);
    stage(1, 1);
    WAIT_VM6();    // stage(0) landed; stage(1)'s 6 loads remain in flight
    BARRIER();

    int buf = 0;
#pragma unroll 1
    for (int t = 0; t < NT; ++t) {
        int tn   = (t + 2 < NT) ? t + 2 : NT - 1;  // clamped dummy at tail
        int bufn = buf + 2 - ((buf >= 1) ? 3 : 0); // (buf+2)%3
        stage(tn, bufn);
        compute(buf);
        WAIT_VM6();   // stage(t+1) landed; stage(t+2) stays in flight
        BARRIER();    // cross-wave: writes visible, buf reads done
        buf = (buf + 1 < 3) ? buf + 1 : 0;
    }

    // ---- epilogue: out = acc * ascale[row] * scales[col] + bias[col] ----
    float sc[4], bs[4];
#pragma unroll
    for (int n = 0; n < 4; ++n) {
        int col = bn * 128 + wn * 64 + n * 16 + r16;
        sc[n] = scales[col];
        bs[n] = bias[col];
    }
#pragma unroll
    for (int mi = 0; mi < 8; ++mi) {
        int row0 = bm * 256 + wm * 128 + mi * 16 + kq * 4;
#pragma unroll
        for (int j = 0; j < 4; ++j) {
            int row = row0 + j;
            float as_ = Ascale[row];
#pragma unroll
            for (int n = 0; n < 4; ++n) {
                int col = bn * 128 + wn * 64 + n * 16 + r16;
                __builtin_nontemporal_store(
                    (float)acc[mi][n][j] * (as_ * sc[n]) + bs[n],
                    &out[(size_t)row * N_DIM + col]);
            }
        }
    }
}

// ---------------- fallback (reg-staged fp16, no workspace needed) ----------------
__global__ __launch_bounds__(256, 2)
void w8a16_gemm(const float* __restrict__ A,
                const void* __restrict__ Wv,
                const float* __restrict__ scales,
                const float* __restrict__ bias,
                float* __restrict__ out) {
    __shared__ char smem[2 * 128 * 64 * 2];
    char* Ash = smem;
    char* Bsh = smem + 128 * 64 * 2;

    const int* wprobe = (const int*)Wv;
    bool wi32 = true;
#pragma unroll
    for (int i = 0; i < 16; ++i) {
        int v = wprobe[i];
        wi32 = wi32 && (v >= -128 && v <= 127);
    }

    const int tid  = threadIdx.x;
    const int lane = tid & 63;
    const int wv   = tid >> 6;
    const int wwm  = wv >> 1;
    const int wwn  = wv & 1;
    const int r16  = lane & 15;
    const int kq   = lane >> 4;
    const int swzl = (r16 & 7) << 4;

    int bid = blockIdx.x;
    int swz = (bid & 7) * 256 + (bid >> 3);
    int bm = swz / 32;
    int bn = swz % 32;

    const int row_a0 = bm * 128;
    const int row_b0 = bn * 128;

    int cr[4], cc[4];
#pragma unroll
    for (int i = 0; i < 4; ++i) {
        int c = tid + 256 * i;
        cr[i] = c >> 3;
        cc[i] = (c & 7) << 3;
    }

    float4 pa[8];
    int4   pbi[8];
    uint2  pb8[4];

    auto load_tile = [&](int kt) {
        int k0 = kt * 64;
#pragma unroll
        for (int i = 0; i < 4; ++i) {
            const float* p = A + (size_t)(row_a0 + cr[i]) * K_DIM + k0 + cc[i];
            pa[2 * i]     = *(const float4*)p;
            pa[2 * i + 1] = *(const float4*)(p + 4);
        }
        if (wi32) {
            const int* w = (const int*)Wv;
#pragma unroll
            for (int i = 0; i < 4; ++i) {
                const int* p = w + (size_t)(row_b0 + cr[i]) * K_DIM + k0 + cc[i];
                pbi[2 * i]     = *(const int4*)p;
                pbi[2 * i + 1] = *(const int4*)(p + 4);
            }
        } else {
            const signed char* w = (const signed char*)Wv;
#pragma unroll
            for (int i = 0; i < 4; ++i) {
                const signed char* p = w + (size_t)(row_b0 + cr[i]) * K_DIM + k0 + cc[i];
                pb8[i] = *(const uint2*)p;
            }
        }
    };

    auto write_lds = [&]() {
#pragma unroll
        for (int i = 0; i < 4; ++i) {
            int off = (cr[i] * 128 + cc[i] * 2) ^ ((cr[i] & 7) << 4);
            half8 h;
            h[0] = (_Float16)pa[2 * i].x;
            h[1] = (_Float16)pa[2 * i].y;
            h[2] = (_Float16)pa[2 * i].z;
            h[3] = (_Float16)pa[2 * i].w;
            h[4] = (_Float16)pa[2 * i + 1].x;
            h[5] = (_Float16)pa[2 * i + 1].y;
            h[6] = (_Float16)pa[2 * i + 1].z;
            h[7] = (_Float16)pa[2 * i + 1].w;
            *(half8*)(Ash + off) = h;

            half8 g;
            if (wi32) {
                g[0] = (_Float16)pbi[2 * i].x;
                g[1] = (_Float16)pbi[2 * i].y;
                g[2] = (_Float16)pbi[2 * i].z;
                g[3] = (_Float16)pbi[2 * i].w;
                g[4] = (_Float16)pbi[2 * i + 1].x;
                g[5] = (_Float16)pbi[2 * i + 1].y;
                g[6] = (_Float16)pbi[2 * i + 1].z;
                g[7] = (_Float16)pbi[2 * i + 1].w;
            } else {
                unsigned x = pb8[i].x, y = pb8[i].y;
                g[0] = (_Float16)(int)(signed char)(x & 0xff);
                g[1] = (_Float16)(int)(signed char)((x >> 8) & 0xff);
                g[2] = (_Float16)(int)(signed char)((x >> 16) & 0xff);
                g[3] = (_Float16)(int)(signed char)(x >> 24);
                g[4] = (_Float16)(int)(signed char)(y & 0xff);
                g[5] = (_Float16)(int)(signed char)((y >> 8) & 0xff);
                g[6] = (_Float16)(int)(signed char)((y >> 16) & 0xff);
                g[7] = (_Float16)(int)(signed char)(y >> 24);
            }
            *(half8*)(Bsh + off) = g;
        }
    };

    f32x4 acc[4][4] = {};

    auto compute = [&]() {
#pragma unroll
        for (int ks = 0; ks < 2; ++ks) {
            half8 af[4], bfr[4];
#pragma unroll
            for (int m = 0; m < 4; ++m) {
                int row = wwm * 64 + m * 16 + r16;
                af[m] = *(const half8*)(Ash + ((row * 128 + ks * 64 + kq * 16) ^ swzl));
            }
#pragma unroll
            for (int n = 0; n < 4; ++n) {
                int row = wwn * 64 + n * 16 + r16;
                bfr[n] = *(const half8*)(Bsh + ((row * 128 + ks * 64 + kq * 16) ^ swzl));
            }
#pragma unroll
            for (int m = 0; m < 4; ++m)
#pragma unroll
                for (int n = 0; n < 4; ++n)
                    acc[m][n] = __builtin_amdgcn_mfma_f32_16x16x32_f16(af[m], bfr[n], acc[m][n], 0, 0, 0);
        }
    };

    load_tile(0);
#pragma unroll 1
    for (int kt = 0; kt < NT; ++kt) {
        if (kt) __syncthreads();
        write_lds();
        __syncthreads();
        if (kt + 1 < NT) load_tile(kt + 1);
        compute();
    }

#pragma unroll
    for (int n = 0; n < 4; ++n) {
        int col = row_b0 + wwn * 64 + n * 16 + r16;
        float s = scales[col];
        float b = bias[col];
#pragma unroll
        for (int m = 0; m < 4; ++m) {
            int row0 = row_a0 + wwm * 64 + m * 16 + kq * 4;
#pragma unroll
            for (int j = 0; j < 4; ++j) {
                out[(size_t)(row0 + j) * N_DIM + col] = acc[m][n][j] * s + b;
            }
        }
    }
}

extern "C" void kernel_launch(void* const* d_in, const int* in_sizes, int n_in,
                              void* d_out, int out_size, void* d_ws, size_t ws_size,
                              hipStream_t stream) {
    const float* A      = (const float*)d_in[0];
    const void*  W      = d_in[1];
    const float* scales = (const float*)d_in[2];
    const float* bias   = (const float*)d_in[3];
    float*       out    = (float*)d_out;

    const size_t needA = (size_t)M_DIM * K_DIM;        // 32 MiB int8
    const size_t needW = (size_t)N_DIM * K_DIM;        // 16 MiB int8
    const size_t needS = (size_t)M_DIM * sizeof(float);

    if (ws_size >= needA + needW + needS) {
        signed char* Apack = (signed char*)d_ws;
        signed char* Wpack = (signed char*)d_ws + needA;
        float*       Asc   = (float*)((char*)d_ws + needA + needW);
        hipLaunchKernelGGL(prep_fused, dim3(12288), dim3(256), 0, stream,
                           A, W, Apack, Wpack, Asc);
        hipLaunchKernelGGL(w8a16_gemm_i8, dim3(1024), dim3(256), 0, stream,
                           Apack, Wpack, Asc, scales, bias, out);
    } else {
        hipLaunchKernelGGL(w8a16_gemm, dim3(2048), dim3(256), 0, stream,
                           A, W, scales, bias, out);
    }
}